// Round 16
// baseline (329.486 us; speedup 1.0000x reference)
//
#include <hip/hip_runtime.h>
#include <hip/hip_bf16.h>
#include <cmath>

// Problem constants
#define Bsz 2
#define Lseq 2048
#define Dmod 1024
#define Hhead 16
#define DH 64
#define HID 4096
#define ROWS (Bsz * Lseq)   // 4096
#define TD (3 * Dmod)       // 3072

typedef __attribute__((ext_vector_type(8))) short bf16x8;
typedef __attribute__((ext_vector_type(4))) float f32x4;
typedef unsigned short ushort_t;

typedef const __attribute__((address_space(1))) void gv_t;
typedef __attribute__((address_space(3))) void lv_t;
#define GLDS16(GP, LP) __builtin_amdgcn_global_load_lds((gv_t*)(GP), (lv_t*)(LP), 16, 0, 0)

__device__ __forceinline__ float bf2f(short u)
{
    return __uint_as_float(((unsigned)(unsigned short)u) << 16);
}
__device__ __forceinline__ unsigned pack2(float a, float b)
{
    __hip_bfloat162 t;
    t.x = __float2bfloat16(a);
    t.y = __float2bfloat16(b);
    return *reinterpret_cast<unsigned*>(&t);
}
__device__ __forceinline__ float gelu_exact(float t)
{
    return 0.5f * t * (1.0f + erff(t * 0.70710678118654752f));
}

// 2-D XCD-aware block remap (round-15 verified: FETCH 118->36 MB).
// Each XCD owns a cn x cm rectangle of the block grid (n-fast inside).
// Bijective: requires cn | gridDim.x, cm | gridDim.y, cn*cm = nwg/8.
__device__ __forceinline__ void xcd_remap2(int cn, int cm, int& mblk, int& nblk)
{
    int nx = gridDim.x;
    int id = blockIdx.y * nx + blockIdx.x;
    int xcd = id & 7;
    int local = id >> 3;
    int gxn = nx / cn;              // XCD grid columns
    int gx = xcd % gxn, gy = xcd / gxn;
    int ln = local % cn, lm = local / cn;
    nblk = gx * cn + ln;
    mblk = gy * cm + lm;
}

// ---------------------------------------------------------------------------
// fp32 -> bf16 conversion of all 4 weight tensors in ONE dispatch.
// blocks: wq 3072 | wo 1024 | wf1 4096 | wf2 4096  (total 12288)
// ---------------------------------------------------------------------------
__global__ __launch_bounds__(256) void f2b4_kernel(const float* __restrict__ s0, ushort_t* __restrict__ d0,
                                                   const float* __restrict__ s1, ushort_t* __restrict__ d1,
                                                   const float* __restrict__ s2, ushort_t* __restrict__ d2,
                                                   const float* __restrict__ s3, ushort_t* __restrict__ d3)
{
    int blk = blockIdx.x;
    const float* src;
    ushort_t* dst;
    int base;
    if (blk < 3072)      { src = s0; dst = d0; base = blk; }
    else if (blk < 4096) { src = s1; dst = d1; base = blk - 3072; }
    else if (blk < 8192) { src = s2; dst = d2; base = blk - 4096; }
    else                 { src = s3; dst = d3; base = blk - 8192; }
    int i = base * 256 + threadIdx.x;
    float4 v = reinterpret_cast<const float4*>(src)[i];
    uint2 o;
    o.x = pack2(v.x, v.y);
    o.y = pack2(v.z, v.w);
    reinterpret_cast<uint2*>(dst)[i] = o;
}

// ---------------------------------------------------------------------------
// LayerNorm: one block per row of D=1024, float4 in, bf16 out.
// ---------------------------------------------------------------------------
__global__ __launch_bounds__(256) void ln_kernel(const float* __restrict__ x,
                                                 const float* __restrict__ g,
                                                 const float* __restrict__ bta,
                                                 ushort_t* __restrict__ out)
{
    int row = blockIdx.x;
    int t = threadIdx.x;
    const float4* xr = reinterpret_cast<const float4*>(x) + (size_t)row * 256;
    float4 v = xr[t];
    float s  = v.x + v.y + v.z + v.w;
    float s2 = v.x * v.x + v.y * v.y + v.z * v.z + v.w * v.w;
#pragma unroll
    for (int o = 32; o > 0; o >>= 1) {
        s  += __shfl_down(s, o);
        s2 += __shfl_down(s2, o);
    }
    __shared__ float sa[4], sb[4];
    int wv = t >> 6, ln = t & 63;
    if (ln == 0) { sa[wv] = s; sb[wv] = s2; }
    __syncthreads();
    s  = sa[0] + sa[1] + sa[2] + sa[3];
    s2 = sb[0] + sb[1] + sb[2] + sb[3];
    float mean = s * (1.0f / 1024.0f);
    float var  = s2 * (1.0f / 1024.0f) - mean * mean;
    float inv  = rsqrtf(var + 1e-5f);
    float4 gv = reinterpret_cast<const float4*>(g)[t];
    float4 bv = reinterpret_cast<const float4*>(bta)[t];
    uint2 o;
    o.x = pack2((v.x - mean) * inv * gv.x + bv.x, (v.y - mean) * inv * gv.y + bv.y);
    o.y = pack2((v.z - mean) * inv * gv.z + bv.z, (v.w - mean) * inv * gv.w + bv.w);
    reinterpret_cast<uint2*>(out)[(size_t)row * 256 + t] = o;
}

// B fragment register block for one K-tile (named members — rule #20).
// b<ni><kk>: ni = N-frag (0,1), kk = K-slice (0,1).
struct BFrag {
    bf16x8 b00, b01, b10, b11;
};

// ---------------------------------------------------------------------------
// bf16 MFMA GEMM body (NT), 128(M) x 64(N) tile, BK=64.
// ROUND-16: B-fragments read DIRECTLY global->VGPR (register double-buffer,
// one tile ahead) — no LDS for B at all. Rationale: the 20-22% MfmaUtil wall
// common to all five prior structures is LDS read BW (12 b128/wave/tile for
// 16 MFMA = 768 B per MFMA vs ~375 B/MFMA LDS-feasible). B needs no
// cross-wave sharing, and 2-D XCD chunking (round 15) keeps the B panel
// L2-resident. A keeps the proven global_load_lds path (2x cross-wave reuse).
// Direct-B address check: the old both-sides swizzle cancels — fragment =
// W + row*ldw + k0 + (kk*4+fg)*8 (same pattern attn_mfma uses for K, proven).
// vmcnt: 8 VMEM ops/tile (4 A-gload_lds + 4 B-loads) -> steady gate vmcnt(8).
// LDS = 32 KB (A dbuf only) -> ~4 blocks/CU (VGPR-capped).
// ---------------------------------------------------------------------------
__device__ __forceinline__ void gemm_n64_body(const ushort_t* __restrict__ A,
                                              const ushort_t* __restrict__ W,
                                              const float* __restrict__ bias,
                                              const float* __restrict__ res,
                                              void* __restrict__ C,
                                              int M, int N, int K, int ldw,
                                              int act, int obf, int cn, int cm)
{
    __shared__ ushort_t As0[128 * 64];   // 16 KB
    __shared__ ushort_t As1[128 * 64];   // 16 KB

    int tid = threadIdx.x;
    int w = tid >> 6, lane = tid & 63;
    int mblk, nblk;
    xcd_remap2(cn, cm, mblk, nblk);
    int m0 = mblk * 128, n0 = nblk * 64;
    int wr = (w >> 1) * 64, wc = (w & 1) * 32;

    int srow = lane >> 3;
    int scol = (((lane & 7) ^ (lane >> 3)) & 7) * 8;   // pre-swizzled source chunk (A)
    const ushort_t* ga[4];
    int laofs[4];
#pragma unroll
    for (int q = 0; q < 4; ++q) {
        ga[q] = A + (size_t)(m0 + w * 32 + q * 8 + srow) * K + scol;
        laofs[q] = (w * 32 + q * 8) * 64;
    }

    int fr = lane & 15;
    int fg = lane >> 4;
    int r0 = fg * 4;
    int cc = fr;

    // direct-B row bases: ni=0 -> rows wc+fr, ni=1 -> rows wc+16+fr
    const ushort_t* gb0 = W + (size_t)(n0 + wc + fr) * ldw + fg * 8;
    const ushort_t* gb1 = W + (size_t)(n0 + wc + 16 + fr) * ldw + fg * 8;

    f32x4 acc[4][2] = {};

    auto stageA = [&](ushort_t* AS, int k0) {
#pragma unroll
        for (int q = 0; q < 4; ++q) GLDS16(ga[q] + k0, AS + laofs[q]);
    };
    auto loadB = [&](BFrag& R, int k0) {
        R.b00 = *reinterpret_cast<const bf16x8*>(gb0 + k0);        // kk=0: chunk fg
        R.b01 = *reinterpret_cast<const bf16x8*>(gb0 + k0 + 32);   // kk=1: chunk 4+fg
        R.b10 = *reinterpret_cast<const bf16x8*>(gb1 + k0);
        R.b11 = *reinterpret_cast<const bf16x8*>(gb1 + k0 + 32);
    };
    auto compute = [&](const ushort_t* AS, const BFrag& R) {
#pragma unroll
        for (int kk = 0; kk < 2; ++kk) {
            bf16x8 af[4];
            int ca = ((kk * 4 + fg) ^ (fr & 7)) * 8;   // swizzled A chunk
#pragma unroll
            for (int i = 0; i < 4; ++i)
                af[i] = *reinterpret_cast<const bf16x8*>(&AS[(wr + i * 16 + fr) * 64 + ca]);
            bf16x8 b0 = kk ? R.b01 : R.b00;
            bf16x8 b1 = kk ? R.b11 : R.b10;
#pragma unroll
            for (int mi = 0; mi < 4; ++mi) {
                acc[mi][0] = __builtin_amdgcn_mfma_f32_16x16x32_bf16(af[mi], b0, acc[mi][0], 0, 0, 0);
                acc[mi][1] = __builtin_amdgcn_mfma_f32_16x16x32_bf16(af[mi], b1, acc[mi][1], 0, 0, 0);
            }
        }
    };

    int nt = K >> 6;    // 16 or 64: even, >= 4
    BFrag Br0, Br1;
    stageA(As0, 0);   loadB(Br0, 0);
    stageA(As1, 64);  loadB(Br1, 64);
    int t = 0;
    for (; t + 3 < nt; t += 2) {
        asm volatile("s_waitcnt vmcnt(8)" ::: "memory");   // tile t (A+B) landed
        __builtin_amdgcn_s_barrier();                      // publish all waves' A
        __builtin_amdgcn_sched_barrier(0);
        compute(As0, Br0);
        __builtin_amdgcn_s_barrier();                      // all reads of As0 done
        stageA(As0, (t + 2) * 64);
        loadB(Br0, (t + 2) * 64);

        asm volatile("s_waitcnt vmcnt(8)" ::: "memory");
        __builtin_amdgcn_s_barrier();
        __builtin_amdgcn_sched_barrier(0);
        compute(As1, Br1);
        __builtin_amdgcn_s_barrier();
        stageA(As1, (t + 3) * 64);
        loadB(Br1, (t + 3) * 64);
    }
    // tail: tiles nt-2 (As0/Br0) and nt-1 (As1/Br1) in flight, no re-stage
    asm volatile("s_waitcnt vmcnt(8)" ::: "memory");
    __builtin_amdgcn_s_barrier();
    __builtin_amdgcn_sched_barrier(0);
    compute(As0, Br0);
    asm volatile("s_waitcnt vmcnt(0)" ::: "memory");
    __builtin_amdgcn_s_barrier();
    __builtin_amdgcn_sched_barrier(0);
    compute(As1, Br1);

    float bv[2];
#pragma unroll
    for (int ni = 0; ni < 2; ++ni)
        bv[ni] = bias ? bias[n0 + wc + ni * 16 + cc] : 0.0f;

#pragma unroll
    for (int mi = 0; mi < 4; ++mi) {
#pragma unroll
        for (int r = 0; r < 4; ++r) {
            int row = m0 + wr + mi * 16 + r0 + r;
            const float* resrow = res ? res + (size_t)row * N : nullptr;
#pragma unroll
            for (int ni = 0; ni < 2; ++ni) {
                int col = n0 + wc + ni * 16 + cc;
                float v = acc[mi][ni][r] + bv[ni];
                if (act == 1) v = gelu_exact(v);
                if (resrow) v += resrow[col];
                if (obf) {
                    reinterpret_cast<ushort_t*>(C)[(size_t)row * N + col] =
                        (ushort_t)__bfloat16_as_ushort(__float2bfloat16(v));
                } else {
                    reinterpret_cast<float*>(C)[(size_t)row * N + col] = v;
                }
            }
        }
    }
}

// QKV / FF1 (K=1024) instances
__global__ __launch_bounds__(256) void gemm_a(const ushort_t* __restrict__ A,
                                              const ushort_t* __restrict__ W,
                                              const float* __restrict__ bias,
                                              const float* __restrict__ res,
                                              void* __restrict__ C,
                                              int M, int N, int K, int ldw,
                                              int act, int obf, int cn, int cm)
{
    gemm_n64_body(A, W, bias, res, C, M, N, K, ldw, act, obf, cn, cm);
}

// O-proj / FF2 instances
__global__ __launch_bounds__(256) void gemm_b(const ushort_t* __restrict__ A,
                                              const ushort_t* __restrict__ W,
                                              const float* __restrict__ bias,
                                              const float* __restrict__ res,
                                              void* __restrict__ C,
                                              int M, int N, int K, int ldw,
                                              int act, int obf, int cn, int cm)
{
    gemm_n64_body(A, W, bias, res, C, M, N, K, ldw, act, obf, cn, cm);
}

// ---------------------------------------------------------------------------
// Flash-style dilated attention via parity compression (round-13 verified,
// V-stage XOR swizzle: 16-way -> 2-way bank conflicts).
// ---------------------------------------------------------------------------
__global__ __launch_bounds__(256) void attn_mfma(const ushort_t* __restrict__ qkv,
                                                 ushort_t* __restrict__ out)
{
    __shared__ ushort_t Vt[64][328];
    __shared__ ushort_t Pw[4][16][40];

    int bid = blockIdx.x;
    int qt = bid & 15, h = (bid >> 4) & 15, p = (bid >> 8) & 1, b = bid >> 9;
    int qt0 = qt * 64;
    int kstart = qt0 - 256;

    const ushort_t* base = qkv + (size_t)b * Lseq * TD;
    int tid = threadIdx.x;

#pragma unroll
    for (int it = 0; it < 10; ++it) {
        int idx = it * 256 + tid;
        int ko = idx >> 3;                 // 0..319
        int dg = idx & 7;                  // dim-group = row>>3
        int kk = kstart + ko;
        bf16x8 v = {};
        if (kk >= 0)
            v = *reinterpret_cast<const bf16x8*>(base + (size_t)(2 * kk + p) * TD + 2048 + h * 64 + dg * 8);
        int kos = ko ^ (dg << 3);          // swizzled column (stays < 320)
#pragma unroll
        for (int j = 0; j < 8; ++j)
            Vt[dg * 8 + j][kos] = (ushort_t)v[j];
    }

    int w = tid >> 6, lane = tid & 63;
    int fr = lane & 15, fg = lane >> 4;
    int qw = qt0 + w * 16;
    const ushort_t* qrow = base + (size_t)(2 * (qw + fr) + p) * TD + h * 64;
    bf16x8 qf0 = *reinterpret_cast<const bf16x8*>(qrow + fg * 8);
    bf16x8 qf1 = *reinterpret_cast<const bf16x8*>(qrow + 32 + fg * 8);

    __syncthreads();

    float m[4]    = {-1e30f, -1e30f, -1e30f, -1e30f};
    float lsum[4] = {};
    f32x4 o[4]    = {};
    const float scale = 0.125f;
    int qbase = qw + fg * 4;

    for (int t = 0; t < 10; ++t) {
        int kt0 = kstart + t * 32;
        int kk0 = kt0 + fr, kk1 = kk0 + 16;
        int kk0c = kk0 < 0 ? 0 : kk0;
        int kk1c = kk1 < 0 ? 0 : kk1;
        const ushort_t* kr0 = base + (size_t)(2 * kk0c + p) * TD + 1024 + h * 64;
        const ushort_t* kr1 = base + (size_t)(2 * kk1c + p) * TD + 1024 + h * 64;
        bf16x8 k00 = *reinterpret_cast<const bf16x8*>(kr0 + fg * 8);
        bf16x8 k01 = *reinterpret_cast<const bf16x8*>(kr0 + 32 + fg * 8);
        bf16x8 k10 = *reinterpret_cast<const bf16x8*>(kr1 + fg * 8);
        bf16x8 k11 = *reinterpret_cast<const bf16x8*>(kr1 + 32 + fg * 8);

        f32x4 s0 = {}, s1 = {};
        s0 = __builtin_amdgcn_mfma_f32_16x16x32_bf16(qf0, k00, s0, 0, 0, 0);
        s0 = __builtin_amdgcn_mfma_f32_16x16x32_bf16(qf1, k01, s0, 0, 0, 0);
        s1 = __builtin_amdgcn_mfma_f32_16x16x32_bf16(qf0, k10, s1, 0, 0, 0);
        s1 = __builtin_amdgcn_mfma_f32_16x16x32_bf16(qf1, k11, s1, 0, 0, 0);

        int c0 = kt0 + fr, c1 = c0 + 16;
        float v0[4], v1[4], tmax[4];
#pragma unroll
        for (int r = 0; r < 4; ++r) {
            int qq = qbase + r;
            bool a0 = (c0 >= 0) && (c0 <= qq) && (c0 >= qq - 256);
            bool a1 = (c1 >= 0) && (c1 <= qq) && (c1 >= qq - 256);
            v0[r] = a0 ? s0[r] * scale : -1e30f;
            v1[r] = a1 ? s1[r] * scale : -1e30f;
            tmax[r] = fmaxf(v0[r], v1[r]);
        }
#pragma unroll
        for (int off = 1; off < 16; off <<= 1) {
#pragma unroll
            for (int r = 0; r < 4; ++r)
                tmax[r] = fmaxf(tmax[r], __shfl_xor(tmax[r], off));
        }
#pragma unroll
        for (int r = 0; r < 4; ++r) {
            float mn = fmaxf(m[r], tmax[r]);
            float corr = __expf(m[r] - mn);
            m[r] = mn;
            float p0 = __expf(v0[r] - mn);
            float p1 = __expf(v1[r] - mn);
            lsum[r] = lsum[r] * corr + p0 + p1;
#pragma unroll
            for (int db = 0; db < 4; ++db)
                o[db][r] *= corr;
            Pw[w][fg * 4 + r][fr]      = (ushort_t)__bfloat16_as_ushort(__float2bfloat16(p0));
            Pw[w][fg * 4 + r][fr + 16] = (ushort_t)__bfloat16_as_ushort(__float2bfloat16(p1));
        }

        bf16x8 pf = *reinterpret_cast<const bf16x8*>(&Pw[w][fr][fg * 8]);
#pragma unroll
        for (int db = 0; db < 4; ++db) {
            int row = db * 16 + fr;
            int colc = (t * 32 + fg * 8) ^ ((row >> 3) << 3);   // un-swizzle
            bf16x8 vf = *reinterpret_cast<const bf16x8*>(&Vt[row][colc]);
            o[db] = __builtin_amdgcn_mfma_f32_16x16x32_bf16(pf, vf, o[db], 0, 0, 0);
        }
    }

#pragma unroll
    for (int off = 1; off < 16; off <<= 1) {
#pragma unroll
        for (int r = 0; r < 4; ++r)
            lsum[r] += __shfl_xor(lsum[r], off);
    }
    float inv[4];
#pragma unroll
    for (int r = 0; r < 4; ++r) inv[r] = 1.0f / lsum[r];

#pragma unroll
    for (int r = 0; r < 4; ++r) {
        size_t orow = ((size_t)b * Lseq + 2 * (qbase + r) + p) * Dmod + h * 64;
#pragma unroll
        for (int db = 0; db < 4; ++db)
            out[orow + db * 16 + fr] =
                (ushort_t)__bfloat16_as_ushort(__float2bfloat16(o[db][r] * inv[r]));
    }
}

// ---------------------------------------------------------------------------
// Launch.  Workspace (bf16 elems), total 33.554M = 67.1 MB:
//   wq 3.146M | wo 1.049M | wf1 4.194M | wf2 4.194M   (bf16 weights)
//   bufFF 16.777M : qkv (12.58M) -> ff1 FULL [4096][4096]  (qkv dead by then)
//   bufH   2.097M : h -> h2
//   bufAtt 2.097M : attnout
// ---------------------------------------------------------------------------
extern "C" void kernel_launch(void* const* d_in, const int* in_sizes, int n_in,
                              void* d_out, int out_size, void* d_ws, size_t ws_size,
                              hipStream_t stream)
{
    const float* x     = (const float*)d_in[0];
    const float* ln1_g = (const float*)d_in[1];
    const float* ln1_b = (const float*)d_in[2];
    const float* w_qkv = (const float*)d_in[3];
    const float* b_qkv = (const float*)d_in[4];
    const float* w_o   = (const float*)d_in[5];
    const float* b_o   = (const float*)d_in[6];
    const float* ln2_g = (const float*)d_in[7];
    const float* ln2_b = (const float*)d_in[8];
    const float* w_ff1 = (const float*)d_in[9];
    const float* b_ff1 = (const float*)d_in[10];
    const float* w_ff2 = (const float*)d_in[11];
    const float* b_ff2 = (const float*)d_in[12];
    float* out = (float*)d_out;

    ushort_t* wq     = (ushort_t*)d_ws;
    ushort_t* wo     = wq  + (size_t)TD * Dmod;
    ushort_t* wf1    = wo  + (size_t)Dmod * Dmod;
    ushort_t* wf2    = wf1 + (size_t)HID * Dmod;
    ushort_t* bufFF  = wf2 + (size_t)Dmod * HID;
    ushort_t* bufH   = bufFF + (size_t)ROWS * HID;
    ushort_t* bufAtt = bufH + (size_t)ROWS * Dmod;

    f2b4_kernel<<<12288, 256, 0, stream>>>(w_qkv, wq, w_o, wo, w_ff1, wf1, w_ff2, wf2);

    // 1. h = LN1(x)
    ln_kernel<<<ROWS, 256, 0, stream>>>(x, ln1_g, ln1_b, bufH);
    // 2. qkv = h @ w_qkv^T + b_qkv  (grid 48x32; XCD chunk 12n x 16m)
    gemm_a<<<dim3(TD / 64, ROWS / 128), 256, 0, stream>>>(bufH, wq, b_qkv, nullptr,
                                                          bufFF, ROWS, TD, Dmod, Dmod, 0, 1,
                                                          12, 16);
    // 3. attnout = flash dilated attention
    attn_mfma<<<Bsz * 2 * Hhead * (1024 / 64), 256, 0, stream>>>(bufFF, bufAtt);
    // 4. out = x + attnout @ w_o^T + b_o  (grid 16x32; XCD chunk 8n x 8m)
    gemm_b<<<dim3(Dmod / 64, ROWS / 128), 256, 0, stream>>>(bufAtt, wo, b_o, x,
                                                            out, ROWS, Dmod, Dmod, Dmod, 0, 0,
                                                            8, 8);
    // 5. h2 = LN2(out)
    ln_kernel<<<ROWS, 256, 0, stream>>>(out, ln2_g, ln2_b, bufH);
    // 6. ff1 = gelu(h2 @ w_ff1^T + b_ff1)  (grid 64x32; XCD chunk 16n x 16m)
    gemm_a<<<dim3(HID / 64, ROWS / 128), 256, 0, stream>>>(bufH, wf1, b_ff1, nullptr,
                                                           bufFF, ROWS, HID, Dmod, Dmod, 1, 1,
                                                           16, 16);
    // 7. out = out + ff1 @ w_ff2^T + b_ff2  (grid 16x32, K=4096; chunk 8n x 8m)
    gemm_b<<<dim3(Dmod / 64, ROWS / 128), 256, 0, stream>>>(bufFF, wf2, b_ff2, out,
                                                            out, ROWS, Dmod, HID, HID, 0, 0,
                                                            8, 8);
}

// Round 18
// 222.065 us; speedup vs baseline: 1.4837x; 1.4837x over previous
//
#include <hip/hip_runtime.h>
#include <hip/hip_bf16.h>
#include <cmath>

// Problem constants
#define Bsz 2
#define Lseq 2048
#define Dmod 1024
#define Hhead 16
#define DH 64
#define HID 4096
#define ROWS (Bsz * Lseq)   // 4096
#define TD (3 * Dmod)       // 3072

typedef __attribute__((ext_vector_type(8))) short bf16x8;
typedef __attribute__((ext_vector_type(4))) float f32x4;
typedef unsigned short ushort_t;

typedef const __attribute__((address_space(1))) void gv_t;
typedef __attribute__((address_space(3))) void lv_t;
#define GLDS16(GP, LP) __builtin_amdgcn_global_load_lds((gv_t*)(GP), (lv_t*)(LP), 16, 0, 0)

__device__ __forceinline__ float bf2f(short u)
{
    return __uint_as_float(((unsigned)(unsigned short)u) << 16);
}
__device__ __forceinline__ unsigned pack2(float a, float b)
{
    __hip_bfloat162 t;
    t.x = __float2bfloat16(a);
    t.y = __float2bfloat16(b);
    return *reinterpret_cast<unsigned*>(&t);
}
__device__ __forceinline__ float gelu_exact(float t)
{
    return 0.5f * t * (1.0f + erff(t * 0.70710678118654752f));
}

// 2-D XCD-aware block remap (round-15 verified: FETCH 118->36 MB).
// Each XCD owns a cn x cm rectangle of the block grid (n-fast inside).
// Bijective: requires cn | gridDim.x, cm | gridDim.y, cn*cm = nwg/8.
__device__ __forceinline__ void xcd_remap2(int cn, int cm, int& mblk, int& nblk)
{
    int nx = gridDim.x;
    int id = blockIdx.y * nx + blockIdx.x;
    int xcd = id & 7;
    int local = id >> 3;
    int gxn = nx / cn;              // XCD grid columns
    int gx = xcd % gxn, gy = xcd / gxn;
    int ln = local % cn, lm = local / cn;
    nblk = gx * cn + ln;
    mblk = gy * cm + lm;
}

// ---------------------------------------------------------------------------
// FUSED: fp32->bf16 conversion of all 4 weight tensors + LN1, one dispatch.
// blocks: wq 3072 | wo 1024 | wf1 4096 | wf2 4096 | LN1 rows 4096 = 16384.
// (param names w0..w3/d0..d3 — round-17 bug: a source param named s2
//  collided with the LN-path local `float s2`.)
// ---------------------------------------------------------------------------
__global__ __launch_bounds__(256) void conv_ln1(const float* __restrict__ w0, ushort_t* __restrict__ d0,
                                                const float* __restrict__ w1, ushort_t* __restrict__ d1,
                                                const float* __restrict__ w2, ushort_t* __restrict__ d2,
                                                const float* __restrict__ w3, ushort_t* __restrict__ d3,
                                                const float* __restrict__ x,
                                                const float* __restrict__ g,
                                                const float* __restrict__ bta,
                                                ushort_t* __restrict__ lnout)
{
    int blk = blockIdx.x;
    int t = threadIdx.x;
    if (blk < 12288) {
        const float* src;
        ushort_t* dst;
        int base;
        if (blk < 3072)      { src = w0; dst = d0; base = blk; }
        else if (blk < 4096) { src = w1; dst = d1; base = blk - 3072; }
        else if (blk < 8192) { src = w2; dst = d2; base = blk - 4096; }
        else                 { src = w3; dst = d3; base = blk - 8192; }
        int i = base * 256 + t;
        float4 v = reinterpret_cast<const float4*>(src)[i];
        uint2 o;
        o.x = pack2(v.x, v.y);
        o.y = pack2(v.z, v.w);
        reinterpret_cast<uint2*>(dst)[i] = o;
        return;
    }
    // LN1 path
    int row = blk - 12288;
    const float4* xr = reinterpret_cast<const float4*>(x) + (size_t)row * 256;
    float4 v = xr[t];
    float sum1 = v.x + v.y + v.z + v.w;
    float sum2 = v.x * v.x + v.y * v.y + v.z * v.z + v.w * v.w;
#pragma unroll
    for (int o = 32; o > 0; o >>= 1) {
        sum1 += __shfl_down(sum1, o);
        sum2 += __shfl_down(sum2, o);
    }
    __shared__ float sa[4], sb[4];
    int wv = t >> 6, ln = t & 63;
    if (ln == 0) { sa[wv] = sum1; sb[wv] = sum2; }
    __syncthreads();
    sum1 = sa[0] + sa[1] + sa[2] + sa[3];
    sum2 = sb[0] + sb[1] + sb[2] + sb[3];
    float mean = sum1 * (1.0f / 1024.0f);
    float var  = sum2 * (1.0f / 1024.0f) - mean * mean;
    float inv  = rsqrtf(var + 1e-5f);
    float4 gv = reinterpret_cast<const float4*>(g)[t];
    float4 bv = reinterpret_cast<const float4*>(bta)[t];
    uint2 o;
    o.x = pack2((v.x - mean) * inv * gv.x + bv.x, (v.y - mean) * inv * gv.y + bv.y);
    o.y = pack2((v.z - mean) * inv * gv.z + bv.z, (v.w - mean) * inv * gv.w + bv.w);
    reinterpret_cast<uint2*>(lnout)[(size_t)row * 256 + t] = o;
}

// ---------------------------------------------------------------------------
// LayerNorm: one block per row of D=1024, float4 in, bf16 out. (LN2)
// ---------------------------------------------------------------------------
__global__ __launch_bounds__(256) void ln_kernel(const float* __restrict__ x,
                                                 const float* __restrict__ g,
                                                 const float* __restrict__ bta,
                                                 ushort_t* __restrict__ out)
{
    int row = blockIdx.x;
    int t = threadIdx.x;
    const float4* xr = reinterpret_cast<const float4*>(x) + (size_t)row * 256;
    float4 v = xr[t];
    float sum1 = v.x + v.y + v.z + v.w;
    float sum2 = v.x * v.x + v.y * v.y + v.z * v.z + v.w * v.w;
#pragma unroll
    for (int o = 32; o > 0; o >>= 1) {
        sum1 += __shfl_down(sum1, o);
        sum2 += __shfl_down(sum2, o);
    }
    __shared__ float sa[4], sb[4];
    int wv = t >> 6, ln = t & 63;
    if (ln == 0) { sa[wv] = sum1; sb[wv] = sum2; }
    __syncthreads();
    sum1 = sa[0] + sa[1] + sa[2] + sa[3];
    sum2 = sb[0] + sb[1] + sb[2] + sb[3];
    float mean = sum1 * (1.0f / 1024.0f);
    float var  = sum2 * (1.0f / 1024.0f) - mean * mean;
    float inv  = rsqrtf(var + 1e-5f);
    float4 gv = reinterpret_cast<const float4*>(g)[t];
    float4 bv = reinterpret_cast<const float4*>(bta)[t];
    uint2 o;
    o.x = pack2((v.x - mean) * inv * gv.x + bv.x, (v.y - mean) * inv * gv.y + bv.y);
    o.y = pack2((v.z - mean) * inv * gv.z + bv.z, (v.w - mean) * inv * gv.w + bv.w);
    reinterpret_cast<uint2*>(out)[(size_t)row * 256 + t] = o;
}

// ---------------------------------------------------------------------------
// bf16 MFMA GEMM body (NT), 128(M) x 64(N) tile, BK=64, XOR chunk-swizzled
// LDS, 2-D XCD remap, counted-vmcnt deep prefetch (round-15 verified best:
// 48 KB LDS -> 3 blocks/CU, FETCH ~36 MB, 61.7 us on FF1).
// ---------------------------------------------------------------------------
__device__ __forceinline__ void gemm_n64_body(const ushort_t* __restrict__ A,
                                              const ushort_t* __restrict__ W,
                                              const float* __restrict__ bias,
                                              const float* __restrict__ res,
                                              void* __restrict__ C,
                                              int M, int N, int K, int ldw,
                                              int act, int obf, int cn, int cm)
{
    __shared__ ushort_t As0[128 * 64];   // 16 KB
    __shared__ ushort_t Bs0[64 * 64];    //  8 KB
    __shared__ ushort_t As1[128 * 64];
    __shared__ ushort_t Bs1[64 * 64];

    int tid = threadIdx.x;
    int w = tid >> 6, lane = tid & 63;
    int mblk, nblk;
    xcd_remap2(cn, cm, mblk, nblk);
    int m0 = mblk * 128, n0 = nblk * 64;
    int wr = (w >> 1) * 64, wc = (w & 1) * 32;

    int srow = lane >> 3;
    int scol = (((lane & 7) ^ (lane >> 3)) & 7) * 8;   // pre-swizzled source chunk
    const ushort_t* ga[4];
    const ushort_t* gb[2];
    int laofs[4], lbofs[2];
#pragma unroll
    for (int q = 0; q < 4; ++q) {
        ga[q] = A + (size_t)(m0 + w * 32 + q * 8 + srow) * K + scol;
        laofs[q] = (w * 32 + q * 8) * 64;
    }
#pragma unroll
    for (int q = 0; q < 2; ++q) {
        gb[q] = W + (size_t)(n0 + w * 16 + q * 8 + srow) * ldw + scol;
        lbofs[q] = (w * 16 + q * 8) * 64;
    }

    int fr = lane & 15;
    int fg = lane >> 4;
    int r0 = fg * 4;
    int cc = fr;

    f32x4 acc[4][2] = {};

    auto stage = [&](ushort_t* AS, ushort_t* BS, int k0) {
#pragma unroll
        for (int q = 0; q < 4; ++q) GLDS16(ga[q] + k0, AS + laofs[q]);
#pragma unroll
        for (int q = 0; q < 2; ++q) GLDS16(gb[q] + k0, BS + lbofs[q]);
    };
    auto compute = [&](const ushort_t* AS, const ushort_t* BS) {
#pragma unroll
        for (int kk = 0; kk < 2; ++kk) {
            bf16x8 af[4], bfr[2];
            int ca = ((kk * 4 + fg) ^ (fr & 7)) * 8;   // swizzled chunk
#pragma unroll
            for (int i = 0; i < 4; ++i)
                af[i] = *reinterpret_cast<const bf16x8*>(&AS[(wr + i * 16 + fr) * 64 + ca]);
#pragma unroll
            for (int i = 0; i < 2; ++i)
                bfr[i] = *reinterpret_cast<const bf16x8*>(&BS[(wc + i * 16 + fr) * 64 + ca]);
#pragma unroll
            for (int mi = 0; mi < 4; ++mi)
#pragma unroll
                for (int ni = 0; ni < 2; ++ni)
                    acc[mi][ni] = __builtin_amdgcn_mfma_f32_16x16x32_bf16(
                        af[mi], bfr[ni], acc[mi][ni], 0, 0, 0);
        }
    };

    int nt = K >> 6;    // 16 or 64: even, >= 4
    stage(As0, Bs0, 0);
    stage(As1, Bs1, 64);
    int t = 0;
    for (; t + 3 < nt; t += 2) {
        asm volatile("s_waitcnt vmcnt(6)" ::: "memory");   // tile t landed; t+1 in flight
        __builtin_amdgcn_s_barrier();
        __builtin_amdgcn_sched_barrier(0);
        compute(As0, Bs0);
        __builtin_amdgcn_s_barrier();
        stage(As0, Bs0, (t + 2) * 64);

        asm volatile("s_waitcnt vmcnt(6)" ::: "memory");
        __builtin_amdgcn_s_barrier();
        __builtin_amdgcn_sched_barrier(0);
        compute(As1, Bs1);
        __builtin_amdgcn_s_barrier();
        stage(As1, Bs1, (t + 3) * 64);
    }
    asm volatile("s_waitcnt vmcnt(6)" ::: "memory");
    __builtin_amdgcn_s_barrier();
    __builtin_amdgcn_sched_barrier(0);
    compute(As0, Bs0);
    asm volatile("s_waitcnt vmcnt(0)" ::: "memory");
    __builtin_amdgcn_s_barrier();
    __builtin_amdgcn_sched_barrier(0);
    compute(As1, Bs1);

    float bv[2];
#pragma unroll
    for (int ni = 0; ni < 2; ++ni)
        bv[ni] = bias ? bias[n0 + wc + ni * 16 + cc] : 0.0f;

#pragma unroll
    for (int mi = 0; mi < 4; ++mi) {
#pragma unroll
        for (int r = 0; r < 4; ++r) {
            int row = m0 + wr + mi * 16 + r0 + r;
            const float* resrow = res ? res + (size_t)row * N : nullptr;
#pragma unroll
            for (int ni = 0; ni < 2; ++ni) {
                int col = n0 + wc + ni * 16 + cc;
                float v = acc[mi][ni][r] + bv[ni];
                if (act == 1) v = gelu_exact(v);
                if (resrow) v += resrow[col];
                if (obf) {
                    reinterpret_cast<ushort_t*>(C)[(size_t)row * N + col] =
                        (ushort_t)__bfloat16_as_ushort(__float2bfloat16(v));
                } else {
                    reinterpret_cast<float*>(C)[(size_t)row * N + col] = v;
                }
            }
        }
    }
}

// QKV / FF1 (K=1024) instances
__global__ __launch_bounds__(256) void gemm_a(const ushort_t* __restrict__ A,
                                              const ushort_t* __restrict__ W,
                                              const float* __restrict__ bias,
                                              const float* __restrict__ res,
                                              void* __restrict__ C,
                                              int M, int N, int K, int ldw,
                                              int act, int obf, int cn, int cm)
{
    gemm_n64_body(A, W, bias, res, C, M, N, K, ldw, act, obf, cn, cm);
}

// O-proj / FF2 instances
__global__ __launch_bounds__(256) void gemm_b(const ushort_t* __restrict__ A,
                                              const ushort_t* __restrict__ W,
                                              const float* __restrict__ bias,
                                              const float* __restrict__ res,
                                              void* __restrict__ C,
                                              int M, int N, int K, int ldw,
                                              int act, int obf, int cn, int cm)
{
    gemm_n64_body(A, W, bias, res, C, M, N, K, ldw, act, obf, cn, cm);
}

// ---------------------------------------------------------------------------
// Flash-style dilated attention via parity compression (round-13 verified,
// V-stage XOR swizzle: 16-way -> 2-way bank conflicts).
// ---------------------------------------------------------------------------
__global__ __launch_bounds__(256) void attn_mfma(const ushort_t* __restrict__ qkv,
                                                 ushort_t* __restrict__ out)
{
    __shared__ ushort_t Vt[64][328];
    __shared__ ushort_t Pw[4][16][40];

    int bid = blockIdx.x;
    int qt = bid & 15, h = (bid >> 4) & 15, p = (bid >> 8) & 1, b = bid >> 9;
    int qt0 = qt * 64;
    int kstart = qt0 - 256;

    const ushort_t* base = qkv + (size_t)b * Lseq * TD;
    int tid = threadIdx.x;

#pragma unroll
    for (int it = 0; it < 10; ++it) {
        int idx = it * 256 + tid;
        int ko = idx >> 3;                 // 0..319
        int dg = idx & 7;                  // dim-group = row>>3
        int kk = kstart + ko;
        bf16x8 v = {};
        if (kk >= 0)
            v = *reinterpret_cast<const bf16x8*>(base + (size_t)(2 * kk + p) * TD + 2048 + h * 64 + dg * 8);
        int kos = ko ^ (dg << 3);          // swizzled column (stays < 320)
#pragma unroll
        for (int j = 0; j < 8; ++j)
            Vt[dg * 8 + j][kos] = (ushort_t)v[j];
    }

    int w = tid >> 6, lane = tid & 63;
    int fr = lane & 15, fg = lane >> 4;
    int qw = qt0 + w * 16;
    const ushort_t* qrow = base + (size_t)(2 * (qw + fr) + p) * TD + h * 64;
    bf16x8 qf0 = *reinterpret_cast<const bf16x8*>(qrow + fg * 8);
    bf16x8 qf1 = *reinterpret_cast<const bf16x8*>(qrow + 32 + fg * 8);

    __syncthreads();

    float m[4]    = {-1e30f, -1e30f, -1e30f, -1e30f};
    float lsum[4] = {};
    f32x4 o[4]    = {};
    const float scale = 0.125f;
    int qbase = qw + fg * 4;

    for (int t = 0; t < 10; ++t) {
        int kt0 = kstart + t * 32;
        int kk0 = kt0 + fr, kk1 = kk0 + 16;
        int kk0c = kk0 < 0 ? 0 : kk0;
        int kk1c = kk1 < 0 ? 0 : kk1;
        const ushort_t* kr0 = base + (size_t)(2 * kk0c + p) * TD + 1024 + h * 64;
        const ushort_t* kr1 = base + (size_t)(2 * kk1c + p) * TD + 1024 + h * 64;
        bf16x8 k00 = *reinterpret_cast<const bf16x8*>(kr0 + fg * 8);
        bf16x8 k01 = *reinterpret_cast<const bf16x8*>(kr0 + 32 + fg * 8);
        bf16x8 k10 = *reinterpret_cast<const bf16x8*>(kr1 + fg * 8);
        bf16x8 k11 = *reinterpret_cast<const bf16x8*>(kr1 + 32 + fg * 8);

        f32x4 s0 = {}, s1 = {};
        s0 = __builtin_amdgcn_mfma_f32_16x16x32_bf16(qf0, k00, s0, 0, 0, 0);
        s0 = __builtin_amdgcn_mfma_f32_16x16x32_bf16(qf1, k01, s0, 0, 0, 0);
        s1 = __builtin_amdgcn_mfma_f32_16x16x32_bf16(qf0, k10, s1, 0, 0, 0);
        s1 = __builtin_amdgcn_mfma_f32_16x16x32_bf16(qf1, k11, s1, 0, 0, 0);

        int c0 = kt0 + fr, c1 = c0 + 16;
        float v0[4], v1[4], tmax[4];
#pragma unroll
        for (int r = 0; r < 4; ++r) {
            int qq = qbase + r;
            bool a0 = (c0 >= 0) && (c0 <= qq) && (c0 >= qq - 256);
            bool a1 = (c1 >= 0) && (c1 <= qq) && (c1 >= qq - 256);
            v0[r] = a0 ? s0[r] * scale : -1e30f;
            v1[r] = a1 ? s1[r] * scale : -1e30f;
            tmax[r] = fmaxf(v0[r], v1[r]);
        }
#pragma unroll
        for (int off = 1; off < 16; off <<= 1) {
#pragma unroll
            for (int r = 0; r < 4; ++r)
                tmax[r] = fmaxf(tmax[r], __shfl_xor(tmax[r], off));
        }
#pragma unroll
        for (int r = 0; r < 4; ++r) {
            float mn = fmaxf(m[r], tmax[r]);
            float corr = __expf(m[r] - mn);
            m[r] = mn;
            float p0 = __expf(v0[r] - mn);
            float p1 = __expf(v1[r] - mn);
            lsum[r] = lsum[r] * corr + p0 + p1;
#pragma unroll
            for (int db = 0; db < 4; ++db)
                o[db][r] *= corr;
            Pw[w][fg * 4 + r][fr]      = (ushort_t)__bfloat16_as_ushort(__float2bfloat16(p0));
            Pw[w][fg * 4 + r][fr + 16] = (ushort_t)__bfloat16_as_ushort(__float2bfloat16(p1));
        }

        bf16x8 pf = *reinterpret_cast<const bf16x8*>(&Pw[w][fr][fg * 8]);
#pragma unroll
        for (int db = 0; db < 4; ++db) {
            int row = db * 16 + fr;
            int colc = (t * 32 + fg * 8) ^ ((row >> 3) << 3);   // un-swizzle
            bf16x8 vf = *reinterpret_cast<const bf16x8*>(&Vt[row][colc]);
            o[db] = __builtin_amdgcn_mfma_f32_16x16x32_bf16(pf, vf, o[db], 0, 0, 0);
        }
    }

#pragma unroll
    for (int off = 1; off < 16; off <<= 1) {
#pragma unroll
        for (int r = 0; r < 4; ++r)
            lsum[r] += __shfl_xor(lsum[r], off);
    }
    float inv[4];
#pragma unroll
    for (int r = 0; r < 4; ++r) inv[r] = 1.0f / lsum[r];

#pragma unroll
    for (int r = 0; r < 4; ++r) {
        size_t orow = ((size_t)b * Lseq + 2 * (qbase + r) + p) * Dmod + h * 64;
#pragma unroll
        for (int db = 0; db < 4; ++db)
            out[orow + db * 16 + fr] =
                (ushort_t)__bfloat16_as_ushort(__float2bfloat16(o[db][r] * inv[r]));
    }
}

// ---------------------------------------------------------------------------
// Launch.  Workspace (bf16 elems), total 33.554M = 67.1 MB:
//   wq 3.146M | wo 1.049M | wf1 4.194M | wf2 4.194M   (bf16 weights)
//   bufFF 16.777M : qkv (12.58M) -> ff1 FULL [4096][4096]  (qkv dead by then)
//   bufH   2.097M : h -> h2
//   bufAtt 2.097M : attnout
// ---------------------------------------------------------------------------
extern "C" void kernel_launch(void* const* d_in, const int* in_sizes, int n_in,
                              void* d_out, int out_size, void* d_ws, size_t ws_size,
                              hipStream_t stream)
{
    const float* x     = (const float*)d_in[0];
    const float* ln1_g = (const float*)d_in[1];
    const float* ln1_b = (const float*)d_in[2];
    const float* w_qkv = (const float*)d_in[3];
    const float* b_qkv = (const float*)d_in[4];
    const float* w_o   = (const float*)d_in[5];
    const float* b_o   = (const float*)d_in[6];
    const float* ln2_g = (const float*)d_in[7];
    const float* ln2_b = (const float*)d_in[8];
    const float* w_ff1 = (const float*)d_in[9];
    const float* b_ff1 = (const float*)d_in[10];
    const float* w_ff2 = (const float*)d_in[11];
    const float* b_ff2 = (const float*)d_in[12];
    float* out = (float*)d_out;

    ushort_t* wq     = (ushort_t*)d_ws;
    ushort_t* wo     = wq  + (size_t)TD * Dmod;
    ushort_t* wf1    = wo  + (size_t)Dmod * Dmod;
    ushort_t* wf2    = wf1 + (size_t)HID * Dmod;
    ushort_t* bufFF  = wf2 + (size_t)Dmod * HID;
    ushort_t* bufH   = bufFF + (size_t)ROWS * HID;
    ushort_t* bufAtt = bufH + (size_t)ROWS * Dmod;

    // 0+1. weight conversion + LN1 fused (16384 blocks)
    conv_ln1<<<16384, 256, 0, stream>>>(w_qkv, wq, w_o, wo, w_ff1, wf1, w_ff2, wf2,
                                        x, ln1_g, ln1_b, bufH);
    // 2. qkv = h @ w_qkv^T + b_qkv  (grid 48x32; XCD chunk 12n x 16m)
    gemm_a<<<dim3(TD / 64, ROWS / 128), 256, 0, stream>>>(bufH, wq, b_qkv, nullptr,
                                                          bufFF, ROWS, TD, Dmod, Dmod, 0, 1,
                                                          12, 16);
    // 3. attnout = flash dilated attention
    attn_mfma<<<Bsz * 2 * Hhead * (1024 / 64), 256, 0, stream>>>(bufFF, bufAtt);
    // 4. out = x + attnout @ w_o^T + b_o  (grid 16x32; XCD chunk 8n x 8m)
    gemm_b<<<dim3(Dmod / 64, ROWS / 128), 256, 0, stream>>>(bufAtt, wo, b_o, x,
                                                            out, ROWS, Dmod, Dmod, Dmod, 0, 0,
                                                            8, 8);
    // 5. h2 = LN2(out)
    ln_kernel<<<ROWS, 256, 0, stream>>>(out, ln2_g, ln2_b, bufH);
    // 6. ff1 = gelu(h2 @ w_ff1^T + b_ff1)  (grid 64x32; XCD chunk 16n x 16m)
    gemm_a<<<dim3(HID / 64, ROWS / 128), 256, 0, stream>>>(bufH, wf1, b_ff1, nullptr,
                                                           bufFF, ROWS, HID, Dmod, Dmod, 1, 1,
                                                           16, 16);
    // 7. out = out + ff1 @ w_ff2^T + b_ff2  (grid 16x32, K=4096; chunk 8n x 8m)
    gemm_b<<<dim3(Dmod / 64, ROWS / 128), 256, 0, stream>>>(bufFF, wf2, b_ff2, out,
                                                            out, ROWS, Dmod, HID, HID, 0, 0,
                                                            8, 8);
}

// Round 19
// 215.850 us; speedup vs baseline: 1.5265x; 1.0288x over previous
//
#include <hip/hip_runtime.h>
#include <hip/hip_bf16.h>
#include <cmath>

// Problem constants
#define Bsz 2
#define Lseq 2048
#define Dmod 1024
#define Hhead 16
#define DH 64
#define HID 4096
#define ROWS (Bsz * Lseq)   // 4096
#define TD (3 * Dmod)       // 3072

typedef __attribute__((ext_vector_type(8))) short bf16x8;
typedef __attribute__((ext_vector_type(4))) float f32x4;
typedef unsigned short ushort_t;

typedef const __attribute__((address_space(1))) void gv_t;
typedef __attribute__((address_space(3))) void lv_t;
#define GLDS16(GP, LP) __builtin_amdgcn_global_load_lds((gv_t*)(GP), (lv_t*)(LP), 16, 0, 0)

__device__ __forceinline__ float bf2f(short u)
{
    return __uint_as_float(((unsigned)(unsigned short)u) << 16);
}
__device__ __forceinline__ unsigned pack2(float a, float b)
{
    __hip_bfloat162 t;
    t.x = __float2bfloat16(a);
    t.y = __float2bfloat16(b);
    return *reinterpret_cast<unsigned*>(&t);
}
__device__ __forceinline__ float gelu_exact(float t)
{
    return 0.5f * t * (1.0f + erff(t * 0.70710678118654752f));
}

// 2-D XCD-aware block remap (round-15 verified: FETCH 118->36 MB).
// Each XCD owns a cn x cm rectangle of the block grid (n-fast inside).
// Bijective: requires cn | gridDim.x, cm | gridDim.y, cn*cm = nwg/8.
__device__ __forceinline__ void xcd_remap2(int cn, int cm, int& mblk, int& nblk)
{
    int nx = gridDim.x;
    int id = blockIdx.y * nx + blockIdx.x;
    int xcd = id & 7;
    int local = id >> 3;
    int gxn = nx / cn;              // XCD grid columns
    int gx = xcd % gxn, gy = xcd / gxn;
    int ln = local % cn, lm = local / cn;
    nblk = gx * cn + ln;
    mblk = gy * cm + lm;
}

// ---------------------------------------------------------------------------
// FUSED: wq conversion + LN1 (only the weight QKV needs first).
// blocks: wq 3072 | LN1 rows 4096  = 7168 total.
// ---------------------------------------------------------------------------
__global__ __launch_bounds__(256) void conv_q_ln1(const float* __restrict__ wsrc, ushort_t* __restrict__ wdst,
                                                  const float* __restrict__ x,
                                                  const float* __restrict__ g,
                                                  const float* __restrict__ bta,
                                                  ushort_t* __restrict__ lnout)
{
    int blk = blockIdx.x;
    int t = threadIdx.x;
    if (blk < 3072) {
        int i = blk * 256 + t;
        float4 v = reinterpret_cast<const float4*>(wsrc)[i];
        uint2 o;
        o.x = pack2(v.x, v.y);
        o.y = pack2(v.z, v.w);
        reinterpret_cast<uint2*>(wdst)[i] = o;
        return;
    }
    int row = blk - 3072;
    const float4* xr = reinterpret_cast<const float4*>(x) + (size_t)row * 256;
    float4 v = xr[t];
    float sum1 = v.x + v.y + v.z + v.w;
    float sum2 = v.x * v.x + v.y * v.y + v.z * v.z + v.w * v.w;
#pragma unroll
    for (int o = 32; o > 0; o >>= 1) {
        sum1 += __shfl_down(sum1, o);
        sum2 += __shfl_down(sum2, o);
    }
    __shared__ float sa[4], sb[4];
    int wv = t >> 6, ln = t & 63;
    if (ln == 0) { sa[wv] = sum1; sb[wv] = sum2; }
    __syncthreads();
    sum1 = sa[0] + sa[1] + sa[2] + sa[3];
    sum2 = sb[0] + sb[1] + sb[2] + sb[3];
    float mean = sum1 * (1.0f / 1024.0f);
    float var  = sum2 * (1.0f / 1024.0f) - mean * mean;
    float inv  = rsqrtf(var + 1e-5f);
    float4 gv = reinterpret_cast<const float4*>(g)[t];
    float4 bv = reinterpret_cast<const float4*>(bta)[t];
    uint2 o;
    o.x = pack2((v.x - mean) * inv * gv.x + bv.x, (v.y - mean) * inv * gv.y + bv.y);
    o.y = pack2((v.z - mean) * inv * gv.z + bv.z, (v.w - mean) * inv * gv.w + bv.w);
    reinterpret_cast<uint2*>(lnout)[(size_t)row * 256 + t] = o;
}

// ---------------------------------------------------------------------------
// LayerNorm: one block per row of D=1024, float4 in, bf16 out. (LN2)
// ---------------------------------------------------------------------------
__global__ __launch_bounds__(256) void ln_kernel(const float* __restrict__ x,
                                                 const float* __restrict__ g,
                                                 const float* __restrict__ bta,
                                                 ushort_t* __restrict__ out)
{
    int row = blockIdx.x;
    int t = threadIdx.x;
    const float4* xr = reinterpret_cast<const float4*>(x) + (size_t)row * 256;
    float4 v = xr[t];
    float sum1 = v.x + v.y + v.z + v.w;
    float sum2 = v.x * v.x + v.y * v.y + v.z * v.z + v.w * v.w;
#pragma unroll
    for (int o = 32; o > 0; o >>= 1) {
        sum1 += __shfl_down(sum1, o);
        sum2 += __shfl_down(sum2, o);
    }
    __shared__ float sa[4], sb[4];
    int wv = t >> 6, ln = t & 63;
    if (ln == 0) { sa[wv] = sum1; sb[wv] = sum2; }
    __syncthreads();
    sum1 = sa[0] + sa[1] + sa[2] + sa[3];
    sum2 = sb[0] + sb[1] + sb[2] + sb[3];
    float mean = sum1 * (1.0f / 1024.0f);
    float var  = sum2 * (1.0f / 1024.0f) - mean * mean;
    float inv  = rsqrtf(var + 1e-5f);
    float4 gv = reinterpret_cast<const float4*>(g)[t];
    float4 bv = reinterpret_cast<const float4*>(bta)[t];
    uint2 o;
    o.x = pack2((v.x - mean) * inv * gv.x + bv.x, (v.y - mean) * inv * gv.y + bv.y);
    o.y = pack2((v.z - mean) * inv * gv.z + bv.z, (v.w - mean) * inv * gv.w + bv.w);
    reinterpret_cast<uint2*>(out)[(size_t)row * 256 + t] = o;
}

// ---------------------------------------------------------------------------
// bf16 MFMA GEMM body (NT), 128(M) x 64(N) tile, BK=64, XOR chunk-swizzled
// LDS, 2-D XCD remap, counted-vmcnt deep prefetch (round-15/18 verified:
// 48 KB LDS -> 3 blocks/CU, FETCH ~36 MB, 61.7 us on FF1).
// ---------------------------------------------------------------------------
__device__ __forceinline__ void gemm_n64_body(const ushort_t* __restrict__ A,
                                              const ushort_t* __restrict__ W,
                                              const float* __restrict__ bias,
                                              const float* __restrict__ res,
                                              void* __restrict__ C,
                                              int M, int N, int K, int ldw,
                                              int act, int obf, int cn, int cm)
{
    __shared__ ushort_t As0[128 * 64];   // 16 KB
    __shared__ ushort_t Bs0[64 * 64];    //  8 KB
    __shared__ ushort_t As1[128 * 64];
    __shared__ ushort_t Bs1[64 * 64];

    int tid = threadIdx.x;
    int w = tid >> 6, lane = tid & 63;
    int mblk, nblk;
    xcd_remap2(cn, cm, mblk, nblk);
    int m0 = mblk * 128, n0 = nblk * 64;
    int wr = (w >> 1) * 64, wc = (w & 1) * 32;

    int srow = lane >> 3;
    int scol = (((lane & 7) ^ (lane >> 3)) & 7) * 8;   // pre-swizzled source chunk
    const ushort_t* ga[4];
    const ushort_t* gb[2];
    int laofs[4], lbofs[2];
#pragma unroll
    for (int q = 0; q < 4; ++q) {
        ga[q] = A + (size_t)(m0 + w * 32 + q * 8 + srow) * K + scol;
        laofs[q] = (w * 32 + q * 8) * 64;
    }
#pragma unroll
    for (int q = 0; q < 2; ++q) {
        gb[q] = W + (size_t)(n0 + w * 16 + q * 8 + srow) * ldw + scol;
        lbofs[q] = (w * 16 + q * 8) * 64;
    }

    int fr = lane & 15;
    int fg = lane >> 4;
    int r0 = fg * 4;
    int cc = fr;

    f32x4 acc[4][2] = {};

    auto stage = [&](ushort_t* AS, ushort_t* BS, int k0) {
#pragma unroll
        for (int q = 0; q < 4; ++q) GLDS16(ga[q] + k0, AS + laofs[q]);
#pragma unroll
        for (int q = 0; q < 2; ++q) GLDS16(gb[q] + k0, BS + lbofs[q]);
    };
    auto compute = [&](const ushort_t* AS, const ushort_t* BS) {
#pragma unroll
        for (int kk = 0; kk < 2; ++kk) {
            bf16x8 af[4], bfr[2];
            int ca = ((kk * 4 + fg) ^ (fr & 7)) * 8;   // swizzled chunk
#pragma unroll
            for (int i = 0; i < 4; ++i)
                af[i] = *reinterpret_cast<const bf16x8*>(&AS[(wr + i * 16 + fr) * 64 + ca]);
#pragma unroll
            for (int i = 0; i < 2; ++i)
                bfr[i] = *reinterpret_cast<const bf16x8*>(&BS[(wc + i * 16 + fr) * 64 + ca]);
#pragma unroll
            for (int mi = 0; mi < 4; ++mi)
#pragma unroll
                for (int ni = 0; ni < 2; ++ni)
                    acc[mi][ni] = __builtin_amdgcn_mfma_f32_16x16x32_bf16(
                        af[mi], bfr[ni], acc[mi][ni], 0, 0, 0);
        }
    };

    int nt = K >> 6;    // 16 or 64: even, >= 4
    stage(As0, Bs0, 0);
    stage(As1, Bs1, 64);
    int t = 0;
    for (; t + 3 < nt; t += 2) {
        asm volatile("s_waitcnt vmcnt(6)" ::: "memory");   // tile t landed; t+1 in flight
        __builtin_amdgcn_s_barrier();
        __builtin_amdgcn_sched_barrier(0);
        compute(As0, Bs0);
        __builtin_amdgcn_s_barrier();
        stage(As0, Bs0, (t + 2) * 64);

        asm volatile("s_waitcnt vmcnt(6)" ::: "memory");
        __builtin_amdgcn_s_barrier();
        __builtin_amdgcn_sched_barrier(0);
        compute(As1, Bs1);
        __builtin_amdgcn_s_barrier();
        stage(As1, Bs1, (t + 3) * 64);
    }
    asm volatile("s_waitcnt vmcnt(6)" ::: "memory");
    __builtin_amdgcn_s_barrier();
    __builtin_amdgcn_sched_barrier(0);
    compute(As0, Bs0);
    asm volatile("s_waitcnt vmcnt(0)" ::: "memory");
    __builtin_amdgcn_s_barrier();
    __builtin_amdgcn_sched_barrier(0);
    compute(As1, Bs1);

    float bv[2];
#pragma unroll
    for (int ni = 0; ni < 2; ++ni)
        bv[ni] = bias ? bias[n0 + wc + ni * 16 + cc] : 0.0f;

#pragma unroll
    for (int mi = 0; mi < 4; ++mi) {
#pragma unroll
        for (int r = 0; r < 4; ++r) {
            int row = m0 + wr + mi * 16 + r0 + r;
            const float* resrow = res ? res + (size_t)row * N : nullptr;
#pragma unroll
            for (int ni = 0; ni < 2; ++ni) {
                int col = n0 + wc + ni * 16 + cc;
                float v = acc[mi][ni][r] + bv[ni];
                if (act == 1) v = gelu_exact(v);
                if (resrow) v += resrow[col];
                if (obf) {
                    reinterpret_cast<ushort_t*>(C)[(size_t)row * N + col] =
                        (ushort_t)__bfloat16_as_ushort(__float2bfloat16(v));
                } else {
                    reinterpret_cast<float*>(C)[(size_t)row * N + col] = v;
                }
            }
        }
    }
}

// QKV / FF1 (K=1024) instances
__global__ __launch_bounds__(256) void gemm_a(const ushort_t* __restrict__ A,
                                              const ushort_t* __restrict__ W,
                                              const float* __restrict__ bias,
                                              const float* __restrict__ res,
                                              void* __restrict__ C,
                                              int M, int N, int K, int ldw,
                                              int act, int obf, int cn, int cm)
{
    gemm_n64_body(A, W, bias, res, C, M, N, K, ldw, act, obf, cn, cm);
}

// O-proj / FF2 instances
__global__ __launch_bounds__(256) void gemm_b(const ushort_t* __restrict__ A,
                                              const ushort_t* __restrict__ W,
                                              const float* __restrict__ bias,
                                              const float* __restrict__ res,
                                              void* __restrict__ C,
                                              int M, int N, int K, int ldw,
                                              int act, int obf, int cn, int cm)
{
    gemm_n64_body(A, W, bias, res, C, M, N, K, ldw, act, obf, cn, cm);
}

// ---------------------------------------------------------------------------
// FUSED: flash dilated attention (blocks 0..1023, launched first) + fp32->bf16
// conversion of wo/wf1/wf2 (blocks 1024..10239). Attention path byte-identical
// to the round-13/18 verified kernel (V-stage XOR swizzle); conversion path is
// the proven streaming copy. Memory-bound conversion hides under the
// compute/latency-bound attention instead of serializing before it.
// ---------------------------------------------------------------------------
__global__ __launch_bounds__(256) void attn_conv(const ushort_t* __restrict__ qkv,
                                                 ushort_t* __restrict__ out,
                                                 const float* __restrict__ w1, ushort_t* __restrict__ d1,
                                                 const float* __restrict__ w2, ushort_t* __restrict__ d2,
                                                 const float* __restrict__ w3, ushort_t* __restrict__ d3)
{
    __shared__ ushort_t Vt[64][328];
    __shared__ ushort_t Pw[4][16][40];

    int bid = blockIdx.x;
    int tid = threadIdx.x;

    if (bid >= 1024) {
        int blk = bid - 1024;
        const float* src;
        ushort_t* dst;
        int base;
        if (blk < 1024)      { src = w1; dst = d1; base = blk; }
        else if (blk < 5120) { src = w2; dst = d2; base = blk - 1024; }
        else                 { src = w3; dst = d3; base = blk - 5120; }
        int i = base * 256 + tid;
        float4 v = reinterpret_cast<const float4*>(src)[i];
        uint2 o;
        o.x = pack2(v.x, v.y);
        o.y = pack2(v.z, v.w);
        reinterpret_cast<uint2*>(dst)[i] = o;
        return;
    }

    int qt = bid & 15, h = (bid >> 4) & 15, p = (bid >> 8) & 1, b = bid >> 9;
    int qt0 = qt * 64;
    int kstart = qt0 - 256;

    const ushort_t* base = qkv + (size_t)b * Lseq * TD;

#pragma unroll
    for (int it = 0; it < 10; ++it) {
        int idx = it * 256 + tid;
        int ko = idx >> 3;                 // 0..319
        int dg = idx & 7;                  // dim-group = row>>3
        int kk = kstart + ko;
        bf16x8 v = {};
        if (kk >= 0)
            v = *reinterpret_cast<const bf16x8*>(base + (size_t)(2 * kk + p) * TD + 2048 + h * 64 + dg * 8);
        int kos = ko ^ (dg << 3);          // swizzled column (stays < 320)
#pragma unroll
        for (int j = 0; j < 8; ++j)
            Vt[dg * 8 + j][kos] = (ushort_t)v[j];
    }

    int w = tid >> 6, lane = tid & 63;
    int fr = lane & 15, fg = lane >> 4;
    int qw = qt0 + w * 16;
    const ushort_t* qrow = base + (size_t)(2 * (qw + fr) + p) * TD + h * 64;
    bf16x8 qf0 = *reinterpret_cast<const bf16x8*>(qrow + fg * 8);
    bf16x8 qf1 = *reinterpret_cast<const bf16x8*>(qrow + 32 + fg * 8);

    __syncthreads();

    float m[4]    = {-1e30f, -1e30f, -1e30f, -1e30f};
    float lsum[4] = {};
    f32x4 o[4]    = {};
    const float scale = 0.125f;
    int qbase = qw + fg * 4;

    for (int t = 0; t < 10; ++t) {
        int kt0 = kstart + t * 32;
        int kk0 = kt0 + fr, kk1 = kk0 + 16;
        int kk0c = kk0 < 0 ? 0 : kk0;
        int kk1c = kk1 < 0 ? 0 : kk1;
        const ushort_t* kr0 = base + (size_t)(2 * kk0c + p) * TD + 1024 + h * 64;
        const ushort_t* kr1 = base + (size_t)(2 * kk1c + p) * TD + 1024 + h * 64;
        bf16x8 k00 = *reinterpret_cast<const bf16x8*>(kr0 + fg * 8);
        bf16x8 k01 = *reinterpret_cast<const bf16x8*>(kr0 + 32 + fg * 8);
        bf16x8 k10 = *reinterpret_cast<const bf16x8*>(kr1 + fg * 8);
        bf16x8 k11 = *reinterpret_cast<const bf16x8*>(kr1 + 32 + fg * 8);

        f32x4 s0 = {}, s1 = {};
        s0 = __builtin_amdgcn_mfma_f32_16x16x32_bf16(qf0, k00, s0, 0, 0, 0);
        s0 = __builtin_amdgcn_mfma_f32_16x16x32_bf16(qf1, k01, s0, 0, 0, 0);
        s1 = __builtin_amdgcn_mfma_f32_16x16x32_bf16(qf0, k10, s1, 0, 0, 0);
        s1 = __builtin_amdgcn_mfma_f32_16x16x32_bf16(qf1, k11, s1, 0, 0, 0);

        int c0 = kt0 + fr, c1 = c0 + 16;
        float v0[4], v1[4], tmax[4];
#pragma unroll
        for (int r = 0; r < 4; ++r) {
            int qq = qbase + r;
            bool a0 = (c0 >= 0) && (c0 <= qq) && (c0 >= qq - 256);
            bool a1 = (c1 >= 0) && (c1 <= qq) && (c1 >= qq - 256);
            v0[r] = a0 ? s0[r] * scale : -1e30f;
            v1[r] = a1 ? s1[r] * scale : -1e30f;
            tmax[r] = fmaxf(v0[r], v1[r]);
        }
#pragma unroll
        for (int off = 1; off < 16; off <<= 1) {
#pragma unroll
            for (int r = 0; r < 4; ++r)
                tmax[r] = fmaxf(tmax[r], __shfl_xor(tmax[r], off));
        }
#pragma unroll
        for (int r = 0; r < 4; ++r) {
            float mn = fmaxf(m[r], tmax[r]);
            float corr = __expf(m[r] - mn);
            m[r] = mn;
            float p0 = __expf(v0[r] - mn);
            float p1 = __expf(v1[r] - mn);
            lsum[r] = lsum[r] * corr + p0 + p1;
#pragma unroll
            for (int db = 0; db < 4; ++db)
                o[db][r] *= corr;
            Pw[w][fg * 4 + r][fr]      = (ushort_t)__bfloat16_as_ushort(__float2bfloat16(p0));
            Pw[w][fg * 4 + r][fr + 16] = (ushort_t)__bfloat16_as_ushort(__float2bfloat16(p1));
        }

        bf16x8 pf = *reinterpret_cast<const bf16x8*>(&Pw[w][fr][fg * 8]);
#pragma unroll
        for (int db = 0; db < 4; ++db) {
            int row = db * 16 + fr;
            int colc = (t * 32 + fg * 8) ^ ((row >> 3) << 3);   // un-swizzle
            bf16x8 vf = *reinterpret_cast<const bf16x8*>(&Vt[row][colc]);
            o[db] = __builtin_amdgcn_mfma_f32_16x16x32_bf16(pf, vf, o[db], 0, 0, 0);
        }
    }

#pragma unroll
    for (int off = 1; off < 16; off <<= 1) {
#pragma unroll
        for (int r = 0; r < 4; ++r)
            lsum[r] += __shfl_xor(lsum[r], off);
    }
    float inv[4];
#pragma unroll
    for (int r = 0; r < 4; ++r) inv[r] = 1.0f / lsum[r];

#pragma unroll
    for (int r = 0; r < 4; ++r) {
        size_t orow = ((size_t)b * Lseq + 2 * (qbase + r) + p) * Dmod + h * 64;
#pragma unroll
        for (int db = 0; db < 4; ++db)
            out[orow + db * 16 + fr] =
                (ushort_t)__bfloat16_as_ushort(__float2bfloat16(o[db][r] * inv[r]));
    }
}

// ---------------------------------------------------------------------------
// Launch.  Workspace (bf16 elems), total 33.554M = 67.1 MB:
//   wq 3.146M | wo 1.049M | wf1 4.194M | wf2 4.194M   (bf16 weights)
//   bufFF 16.777M : qkv (12.58M) -> ff1 FULL [4096][4096]  (qkv dead by then)
//   bufH   2.097M : h -> h2
//   bufAtt 2.097M : attnout
// Schedule: conv(wq)+LN1 -> QKV -> [attn || conv(wo,wf1,wf2)] -> O-proj
//           -> LN2 -> FF1 -> FF2.
// ---------------------------------------------------------------------------
extern "C" void kernel_launch(void* const* d_in, const int* in_sizes, int n_in,
                              void* d_out, int out_size, void* d_ws, size_t ws_size,
                              hipStream_t stream)
{
    const float* x     = (const float*)d_in[0];
    const float* ln1_g = (const float*)d_in[1];
    const float* ln1_b = (const float*)d_in[2];
    const float* w_qkv = (const float*)d_in[3];
    const float* b_qkv = (const float*)d_in[4];
    const float* w_o   = (const float*)d_in[5];
    const float* b_o   = (const float*)d_in[6];
    const float* ln2_g = (const float*)d_in[7];
    const float* ln2_b = (const float*)d_in[8];
    const float* w_ff1 = (const float*)d_in[9];
    const float* b_ff1 = (const float*)d_in[10];
    const float* w_ff2 = (const float*)d_in[11];
    const float* b_ff2 = (const float*)d_in[12];
    float* out = (float*)d_out;

    ushort_t* wq     = (ushort_t*)d_ws;
    ushort_t* wo     = wq  + (size_t)TD * Dmod;
    ushort_t* wf1    = wo  + (size_t)Dmod * Dmod;
    ushort_t* wf2    = wf1 + (size_t)HID * Dmod;
    ushort_t* bufFF  = wf2 + (size_t)Dmod * HID;
    ushort_t* bufH   = bufFF + (size_t)ROWS * HID;
    ushort_t* bufAtt = bufH + (size_t)ROWS * Dmod;

    // 0+1. wq conversion + LN1 (7168 blocks)
    conv_q_ln1<<<7168, 256, 0, stream>>>(w_qkv, wq, x, ln1_g, ln1_b, bufH);
    // 2. qkv = h @ w_qkv^T + b_qkv  (grid 48x32; XCD chunk 12n x 16m)
    gemm_a<<<dim3(TD / 64, ROWS / 128), 256, 0, stream>>>(bufH, wq, b_qkv, nullptr,
                                                          bufFF, ROWS, TD, Dmod, Dmod, 0, 1,
                                                          12, 16);
    // 3. attnout = flash dilated attention  ||  convert wo/wf1/wf2 (10240 blocks)
    attn_conv<<<10240, 256, 0, stream>>>(bufFF, bufAtt, w_o, wo, w_ff1, wf1, w_ff2, wf2);
    // 4. out = x + attnout @ w_o^T + b_o  (grid 16x32; XCD chunk 8n x 8m)
    gemm_b<<<dim3(Dmod / 64, ROWS / 128), 256, 0, stream>>>(bufAtt, wo, b_o, x,
                                                            out, ROWS, Dmod, Dmod, Dmod, 0, 0,
                                                            8, 8);
    // 5. h2 = LN2(out)
    ln_kernel<<<ROWS, 256, 0, stream>>>(out, ln2_g, ln2_b, bufH);
    // 6. ff1 = gelu(h2 @ w_ff1^T + b_ff1)  (grid 64x32; XCD chunk 16n x 16m)
    gemm_a<<<dim3(HID / 64, ROWS / 128), 256, 0, stream>>>(bufH, wf1, b_ff1, nullptr,
                                                           bufFF, ROWS, HID, Dmod, Dmod, 1, 1,
                                                           16, 16);
    // 7. out = out + ff1 @ w_ff2^T + b_ff2  (grid 16x32, K=4096; chunk 8n x 8m)
    gemm_b<<<dim3(Dmod / 64, ROWS / 128), 256, 0, stream>>>(bufFF, wf2, b_ff2, out,
                                                            out, ROWS, Dmod, HID, HID, 0, 0,
                                                            8, 8);
}